// Round 23
// baseline (200.184 us; speedup 1.0000x reference)
//
#include <hip/hip_runtime.h>

#define LOSS_OFF 8388608
#define IDX_OFF  8388609

// ws layout (bytes)
#define WS_SEE   0          // float[1024]
#define WS_KEY   4096       // u64[32768]   -> 266240
#define WS_LOSS  266240     // double
#define WS_EP    266248     // packed E frags (1 MB), 8-aligned

#define FLT_BIG  3.402823466e+38f
#define MARGIN   1.0e-4f

typedef __attribute__((ext_vector_type(8))) short  short8v;
typedef __attribute__((ext_vector_type(4))) float  float4v;

// async global->LDS, 16B per lane; LDS dest = wave-uniform base (+ lane*16 by HW)
#define GLD16(gp, lp) __builtin_amdgcn_global_load_lds( \
    (const __attribute__((address_space(1))) unsigned int*)(gp), \
    (__attribute__((address_space(3))) unsigned int*)(lp), 16, 0, 0)

// numpy pairwise_sum of 256 squared elements, bit-exact (round-2 notes).
__device__ __forceinline__ float np_sumsq256(const float* __restrict__ p, int stride) {
    float s[2];
#pragma unroll
    for (int half = 0; half < 2; half++) {
        const float* a = p + half * 128 * stride;
        float r[8];
#pragma unroll
        for (int l = 0; l < 8; l++) {
            float v = a[l * stride];
            float sq = v * v;
            asm volatile("" : "+v"(sq));   // forbid fma contraction
            r[l] = sq;
        }
#pragma unroll
        for (int i = 8; i < 128; i += 8) {
#pragma unroll
            for (int l = 0; l < 8; l++) {
                float v = a[(i + l) * stride];
                float sq = v * v;
                asm volatile("" : "+v"(sq));
                r[l] = r[l] + sq;
            }
        }
        s[half] = ((r[0] + r[1]) + (r[2] + r[3])) + ((r[4] + r[5]) + (r[6] + r[7]));
    }
    return s[0] + s[1];
}

__device__ __forceinline__ unsigned int f32_sortable(float m) {
    unsigned int u = __float_as_uint(m);
    return u ^ (((unsigned int)((int)u >> 31)) | 0x80000000u);
}
__device__ __forceinline__ float f32_unsortable(unsigned int s) {   // inverse
    const unsigned int u = (s >> 31) ? (s ^ 0x80000000u) : ~s;
    return __uint_as_float(u);
}

__device__ __forceinline__ unsigned short f2bf(float f) {      // RNE float->bf16
    unsigned int u = __float_as_uint(f);
    return (unsigned short)((u + 0x7fffu + ((u >> 16) & 1u)) >> 16);
}
__device__ __forceinline__ float bf2f(unsigned short h) {
    return __uint_as_float(((unsigned int)h) << 16);
}

// ---------------- k_prep: epack (0..255) + see/init (256..259) + eT (260..323) ----------------
__global__ __launch_bounds__(256) void k_prep(const float* __restrict__ emb,
                                              unsigned short* __restrict__ ebP,
                                              float* __restrict__ see,
                                              float* __restrict__ eT,
                                              double* __restrict__ loss) {
    const int t = threadIdx.x, bb = blockIdx.x;
    if (bb < 256) {
        const int idx = bb * 256 + t;
        const int l  = idx & 63;
        const int ph = (idx >> 6) & 1;
        const int ct = (idx >> 7) & 7;
        const int cc = (idx >> 10) & 7;
        const int cg = (idx >> 13) & 7;
        const int row = cg * 128 + ct * 16 + (l & 15);
        const int col = cc * 32 + (l >> 4) * 8;
        const float* src = emb + (size_t)row * 256 + col;
        uint4 out;
        unsigned short* op = (unsigned short*)&out;
#pragma unroll
        for (int i = 0; i < 8; i++) {
            const float v = src[i];
            const unsigned short h = f2bf(v);
            op[i] = ph ? f2bf(v - bf2f(h)) : h;      // v-h exact (Sterbenz)
        }
        *(uint4*)(ebP + (size_t)idx * 8) = out;
    } else if (bb < 260) {
        const int k = (bb - 256) * 256 + t;
        see[k] = np_sumsq256(emb + (size_t)k * 256, 1);
        if (k == 0) { *loss = 0.0; }
    } else {
        // transpose 16 codes -> eT[c][k] (in d_out's quantized region; k1 rescan reads, k3 overwrites)
        __shared__ float T[256][17];
        const int k0 = (bb - 260) << 4;
        const int kr = t >> 4, cs = (t & 15) << 4;
#pragma unroll
        for (int j = 0; j < 4; j++) {
            const float4 v = *(const float4*)(emb + (size_t)(k0 + kr) * 256 + cs + j * 4);
            T[cs + j * 4 + 0][kr] = v.x;
            T[cs + j * 4 + 1][kr] = v.y;
            T[cs + j * 4 + 2][kr] = v.z;
            T[cs + j * 4 + 3][kr] = v.w;
        }
        __syncthreads();
        float* dst = eT + (size_t)t * 1024 + k0;
#pragma unroll
        for (int j = 0; j < 4; j++) {
            float4 v;
            v.x = T[t][j * 4 + 0]; v.y = T[t][j * 4 + 1];
            v.z = T[t][j * 4 + 2]; v.w = T[t][j * 4 + 3];
            *(float4*)(dst + j * 4) = v;
        }
    }
}

// issue 8 B-loads (4 ct, hi+lo) into a register buffer -- static indices only
#define LOADB(buf, ccv, cth) do {                                              \
    _Pragma("unroll")                                                          \
    for (int q = 0; q < 4; q++) {                                              \
        const int ctq = (cth) * 4 + q;                                         \
        const size_t bbq = ((((size_t)codeg * 8 + (ccv)) * 8 + ctq) * 2) * 512 \
                           + (size_t)l * 8;                                    \
        buf[2 * q]     = *(const short8v*)(ebP + bbq);                         \
        buf[2 * q + 1] = *(const short8v*)(ebP + bbq + 512);                   \
    }                                                                          \
} while (0)

// 12 MFMAs for one ct (3-product accumulate) -- order identical to rounds 14-22
#define MFMA_CT(ctv, BH, BL) do {                                              \
    _Pragma("unroll")                                                          \
    for (int at = 0; at < 4; at++) {                                           \
        acc[at][ctv] = __builtin_amdgcn_mfma_f32_16x16x32_bf16(ah[at], BH, acc[at][ctv], 0, 0, 0); \
        acc[at][ctv] = __builtin_amdgcn_mfma_f32_16x16x32_bf16(ah[at], BL, acc[at][ctv], 0, 0, 0); \
        acc[at][ctv] = __builtin_amdgcn_mfma_f32_16x16x32_bf16(al[at], BH, acc[at][ctv], 0, 0, 0); \
    }                                                                          \
} while (0)

// ---------------- k1: fused stage+split+sxx+screen+loss+IN-BLOCK RESCAN ----------------
// grid 512 x 512 thr. LDS 129 KB: xstage 64K | frag 64K | tail 1K (sxs/flg/red8).
// Fold's lk1/lg2 live in the frag region (dead after MFMA loop; extra barrier) so
// xstage SURVIVES -> flagged rows are np-exact-rescanned in-block: thread t owns
// codes {t, t+512}; x from LDS (broadcast), eT coalesced from d_out (L2-resident);
// single-writer key[n], no atomics. Replaces the k2r launch (+~10us gap) and kills
// wl/cnt/sxx globals. ~0.5 flagged rows/block (margin 1e-4) -> ~0.5us tail.
__global__ __launch_bounds__(512, 2) void k1_mfma(
        const float* __restrict__ x,
        const unsigned short* __restrict__ ebP,
        const float* __restrict__ see_g,
        const float* __restrict__ eT,
        unsigned long long* __restrict__ key,
        double* __restrict__ loss) {
    __shared__ char smem[132096];
    float* xstage = (float*)smem;                                  // [0,64K)
    char*  frag   = smem + 65536;                                  // [64K,128K)
    unsigned long long* lk1 = (unsigned long long*)frag;           // post-loop alias, 4 KB
    float*              lg2 = (float*)(frag + 4096);               // 2 KB
    float*              sxs = (float*)(smem + 131072);             // 256 B
    int*                flg = (int*)(smem + 131328);               // 256 B
    unsigned long long* red8 = (unsigned long long*)(smem + 131584); // 64 B

    const int t = threadIdx.x;
    const int w = t >> 6, l = t & 63;
    const int codeg = w;
    const int lrow = l >> 4, lcol = l & 15;
    const int rb = blockIdx.x;
    const int n0 = rb * 64;
    const int b  = rb >> 4;
    const int hw0 = (rb & 15) << 6;

    // Phase A: stage x -> LDS [c][row] f32 (64 KB, linear GLD16)
    {
        const char* xbyte = (const char*)x + ((size_t)b * 262144 + hw0) * 4;
#pragma unroll
        for (int i = 0; i < 8; i++) {
            const int cbase = i * 32 + w * 4;
            const char* src = xbyte + (size_t)(cbase + (l >> 4)) * 4096 + (size_t)(l & 15) * 16;
            GLD16(src, smem + cbase * 256);
        }
    }
    __syncthreads();

    // Phase C: cooperative bf16 hi/lo split -> packed fragments
#pragma unroll
    for (int ii = 0; ii < 4; ii++) {
        const int pi  = ii * 512 + t;          // 0..2047 = [cc(8)][at(4)][l(64)]
        const int pcc = pi >> 8;
        const int pat = (pi >> 6) & 3;
        const int pl  = pi & 63;
        const int prow = pat * 16 + (pl & 15);
        const int pc0  = pcc * 32 + (pl >> 4) * 8;
        uint4 hp, lp;
        unsigned short* hpp = (unsigned short*)&hp;
        unsigned short* lpp = (unsigned short*)&lp;
#pragma unroll
        for (int i = 0; i < 8; i++) {
            const float v = xstage[(pc0 + i) * 64 + prow];
            const unsigned short h = f2bf(v);
            hpp[i] = h;
            lpp[i] = f2bf(v - bf2f(h));        // exact (Sterbenz)
        }
        char* dst = frag + pcc * 8192 + pat * 2048 + pl * 16;
        *(uint4*)dst = hp;
        *(uint4*)(dst + 1024) = lp;
    }
    // Phase B: per-row ||x||^2, np-exact (wave 0; one row per lane)
    float sx_reg = 0.f;
    if (t < 64) {
        sx_reg = np_sumsq256(xstage + t, 64);
        sxs[t] = sx_reg;
    }
    __syncthreads();                            // frags+sxs ready

    float4v acc[4][8];
#pragma unroll
    for (int at = 0; at < 4; at++)
#pragma unroll
        for (int ct = 0; ct < 8; ct++) acc[at][ct] = (float4v){0.f, 0.f, 0.f, 0.f};

    short8v b0[8], b1[8];
    LOADB(b0, 0, 0);                            // prime: (cc=0, half 0)
    for (int cc = 0; cc < 8; cc++) {
        short8v ah[4], al[4];
#pragma unroll
        for (int at = 0; at < 4; at++) {
            const int off = cc * 8192 + at * 2048 + l * 16;
            ah[at] = *(const short8v*)(frag + off);
            al[at] = *(const short8v*)(frag + off + 1024);
        }
        LOADB(b1, cc, 1);                       // issue half 1 before computing half 0
        MFMA_CT(0, b0[0], b0[1]);
        MFMA_CT(1, b0[2], b0[3]);
        MFMA_CT(2, b0[4], b0[5]);
        MFMA_CT(3, b0[6], b0[7]);
        if (cc < 7) LOADB(b0, cc + 1, 0);       // next cc's half 0 under half 1's MFMAs
        MFMA_CT(4, b1[0], b1[1]);
        MFMA_CT(5, b1[2], b1[3]);
        MFMA_CT(6, b1[4], b1[5]);
        MFMA_CT(7, b1[6], b1[7]);
    }
    __syncthreads();                            // all waves done reading frag -> lk1/lg2 may alias

    float sv[8];
#pragma unroll
    for (int ct = 0; ct < 8; ct++) sv[ct] = see_g[codeg * 128 + ct * 16 + lcol];

    // per-row top-2 of g = see - 2*dot_est  (sxx row-constant: order-neutral)
#pragma unroll
    for (int at = 0; at < 4; at++) {
#pragma unroll
        for (int j = 0; j < 4; j++) {
            unsigned long long K1 = ~0ull; float G1 = FLT_BIG, G2 = FLT_BIG;
#pragma unroll
            for (int ct = 0; ct < 8; ct++) {
                const float g = fmaf(-2.f, acc[at][ct][j], sv[ct]);
                const int k = codeg * 128 + ct * 16 + lcol;
                const unsigned long long pk =
                    ((unsigned long long)f32_sortable(g) << 32) | (unsigned int)k;
                if (pk < K1) { G2 = G1; K1 = pk; G1 = g; }
                else         { G2 = fminf(G2, g); }
            }
#pragma unroll
            for (int m = 1; m < 16; m <<= 1) {
                const unsigned long long oK = __shfl_xor(K1, m, 64);
                const float oG2 = __shfl_xor(G2, m, 64);
                const float oG1 = f32_unsortable((unsigned int)(oK >> 32));
                if (oK < K1) { G2 = fminf(oG2, G1); K1 = oK; G1 = oG1; }
                else         { G2 = fminf(G2, oG1); }
            }
            const int rloc = at * 16 + lrow * 4 + j;
            if (lcol == 0) { lk1[rloc * 8 + codeg] = K1; lg2[rloc * 8 + codeg] = G2; }
        }
    }
    __syncthreads();
    if (t < 64) {
        unsigned long long K1 = ~0ull; float G1 = FLT_BIG, G2 = FLT_BIG;
        for (int cg = 0; cg < 8; cg++) {
            const unsigned long long oK = lk1[t * 8 + cg];
            const float oG2 = lg2[t * 8 + cg];
            const float oG1 = f32_unsortable((unsigned int)(oK >> 32));
            if (oK < K1) { G2 = fminf(oG2, G1); K1 = oK; G1 = oG1; }
            else         { G2 = fminf(G2, oG1); }
        }
        const int n = n0 + t;
        const int flagged = (G2 - G1 <= MARGIN);
        flg[t] = flagged;
        if (!flagged) key[n] = K1;              // flagged rows written by rescan below
        // loss partial: sum over this block's 64 rows of (sxx + min-dist est)
        float part = sx_reg + G1;
#pragma unroll
        for (int m = 1; m < 64; m <<= 1) part += __shfl_xor(part, m, 64);
        if (t == 0) atomicAdd(loss, (double)part);
    }
    __syncthreads();                            // flg visible to all threads

    // In-block np-exact rescan of flagged rows (thread t: codes t, t+512)
    for (int r = 0; r < 64; r++) {
        if (!flg[r]) continue;                  // uniform branch (LDS flag)
        const float sx = sxs[r];
        float d0 = 0.f, d1 = 0.f;
#pragma unroll 4
        for (int c = 0; c < 256; c++) {
            const float xv = xstage[c * 64 + r];              // LDS broadcast
            d0 = fmaf(xv, eT[(size_t)c * 1024 + t], d0);       // coalesced
            d1 = fmaf(xv, eT[(size_t)c * 1024 + t + 512], d1);
        }
        const float q0 = fmaf(-2.f, d0, sx) + see_g[t];
        const float q1 = fmaf(-2.f, d1, sx) + see_g[t + 512];
        unsigned long long best =
            ((unsigned long long)f32_sortable(q0) << 32) | (unsigned int)t;
        const unsigned long long pk1 =
            ((unsigned long long)f32_sortable(q1) << 32) | (unsigned int)(t + 512);
        best = pk1 < best ? pk1 : best;
#pragma unroll
        for (int m = 1; m < 64; m <<= 1) {
            const unsigned long long o = __shfl_xor(best, m, 64);
            best = o < best ? o : best;
        }
        if (l == 0) red8[w] = best;
        __syncthreads();
        if (t == 0) {
            unsigned long long mkey = red8[0];
            for (int i = 1; i < 8; i++) mkey = red8[i] < mkey ? red8[i] : mkey;
            key[n0 + r] = mkey;                 // single writer
        }
        __syncthreads();
    }
}

// ---------------- k3: gather quantized + indices + loss finalize ----------------
__global__ __launch_bounds__(256) void k3_out(const float* __restrict__ emb,
                                              const unsigned long long* __restrict__ key,
                                              const double* __restrict__ loss,
                                              float* __restrict__ dout) {
    __shared__ float elds[32][257];
    __shared__ int   idxs[32];
    const int t  = threadIdx.x;
    const int bh = blockIdx.x;
    const int b = bh >> 5, h = bh & 31;
    if (t < 32) idxs[t] = (int)(key[(bh << 5) + t] & 0xffffffffull);
    __syncthreads();
    for (int r = 0; r < 32; r++) elds[r][t] = emb[(size_t)idxs[r] * 256 + t];
    __syncthreads();
    const int w = t & 31, cg = t >> 5;
    const size_t base = (size_t)b * 262144 + (size_t)(h * 32 + w);
#pragma unroll 4
    for (int s = 0; s < 32; s++) {
        const int c = (cg << 5) + s;
        dout[base + (size_t)c * 1024] = elds[w][c];
    }
    if (t < 32) dout[IDX_OFF + (bh << 5) + t] = (float)idxs[t];
    if (bh == 0 && t == 0)
        dout[LOSS_OFF] = (float)(1.25 * (*loss) / 8388608.0);
}

extern "C" void kernel_launch(void* const* d_in, const int* in_sizes, int n_in,
                              void* d_out, int out_size, void* d_ws, size_t ws_size,
                              hipStream_t stream) {
    const float* x   = (const float*)d_in[0];
    const float* emb = (const float*)d_in[1];
    float* dout = (float*)d_out;
    char* ws = (char*)d_ws;
    float*  see  = (float*)(ws + WS_SEE);
    unsigned long long* key = (unsigned long long*)(ws + WS_KEY);
    double* loss = (double*)(ws + WS_LOSS);
    unsigned short* ebP = (unsigned short*)(ws + WS_EP);
    // eT (exact f32 transpose for the in-k1 rescan) lives in d_out's quantized
    // region: written by k_prep, read by k1 (which never writes d_out), then
    // overwritten by k3.
    float* eT = dout;

    k_prep <<<324,  256, 0, stream>>>(emb, ebP, see, eT, loss);
    k1_mfma<<<512,  512, 0, stream>>>(x, ebP, see, eT, key, loss);
    k3_out <<<1024, 256, 0, stream>>>(emb, key, loss, dout);
}

// Round 24
// 178.725 us; speedup vs baseline: 1.1201x; 1.1201x over previous
//
#include <hip/hip_runtime.h>

#define LOSS_OFF 8388608
#define IDX_OFF  8388609

// ws layout (bytes)  (total ~1.58 MB)
#define WS_SEE   0          // float[1024]
#define WS_SXX   4096       // float[32768]   -> 135168
#define WS_KEY   135168     // u64[32768]     -> 397312
#define WS_CNT   397312     // int
#define WS_LOSS  397320     // double
#define WS_WL    397328     // int[32768]     -> 528400
#define WS_EP    528448     // packed E frags (1 MB)

#define FLT_BIG  3.402823466e+38f
#define MARGIN   1.0e-4f

typedef __attribute__((ext_vector_type(8))) short  short8v;
typedef __attribute__((ext_vector_type(4))) float  float4v;

// async global->LDS, 16B per lane; LDS dest = wave-uniform base (+ lane*16 by HW)
#define GLD16(gp, lp) __builtin_amdgcn_global_load_lds( \
    (const __attribute__((address_space(1))) unsigned int*)(gp), \
    (__attribute__((address_space(3))) unsigned int*)(lp), 16, 0, 0)

// numpy pairwise_sum of 256 squared elements, bit-exact (round-2 notes).
__device__ __forceinline__ float np_sumsq256(const float* __restrict__ p, int stride) {
    float s[2];
#pragma unroll
    for (int half = 0; half < 2; half++) {
        const float* a = p + half * 128 * stride;
        float r[8];
#pragma unroll
        for (int l = 0; l < 8; l++) {
            float v = a[l * stride];
            float sq = v * v;
            asm volatile("" : "+v"(sq));   // forbid fma contraction
            r[l] = sq;
        }
#pragma unroll
        for (int i = 8; i < 128; i += 8) {
#pragma unroll
            for (int l = 0; l < 8; l++) {
                float v = a[(i + l) * stride];
                float sq = v * v;
                asm volatile("" : "+v"(sq));
                r[l] = r[l] + sq;
            }
        }
        s[half] = ((r[0] + r[1]) + (r[2] + r[3])) + ((r[4] + r[5]) + (r[6] + r[7]));
    }
    return s[0] + s[1];
}

__device__ __forceinline__ unsigned int f32_sortable(float m) {
    unsigned int u = __float_as_uint(m);
    return u ^ (((unsigned int)((int)u >> 31)) | 0x80000000u);
}
__device__ __forceinline__ float f32_unsortable(unsigned int s) {   // inverse
    const unsigned int u = (s >> 31) ? (s ^ 0x80000000u) : ~s;
    return __uint_as_float(u);
}

__device__ __forceinline__ unsigned short f2bf(float f) {      // RNE float->bf16
    unsigned int u = __float_as_uint(f);
    return (unsigned short)((u + 0x7fffu + ((u >> 16) & 1u)) >> 16);
}
__device__ __forceinline__ float bf2f(unsigned short h) {
    return __uint_as_float(((unsigned int)h) << 16);
}

// ---------------- k_prep: epack (0..255) + see/init (256..259) + eT (260..323) ----------------
__global__ __launch_bounds__(256) void k_prep(const float* __restrict__ emb,
                                              unsigned short* __restrict__ ebP,
                                              float* __restrict__ see,
                                              float* __restrict__ eT,
                                              int* __restrict__ cnt,
                                              double* __restrict__ loss) {
    const int t = threadIdx.x, bb = blockIdx.x;
    if (bb < 256) {
        const int idx = bb * 256 + t;
        const int l  = idx & 63;
        const int ph = (idx >> 6) & 1;
        const int ct = (idx >> 7) & 7;
        const int cc = (idx >> 10) & 7;
        const int cg = (idx >> 13) & 7;
        const int row = cg * 128 + ct * 16 + (l & 15);
        const int col = cc * 32 + (l >> 4) * 8;
        const float* src = emb + (size_t)row * 256 + col;
        uint4 out;
        unsigned short* op = (unsigned short*)&out;
#pragma unroll
        for (int i = 0; i < 8; i++) {
            const float v = src[i];
            const unsigned short h = f2bf(v);
            op[i] = ph ? f2bf(v - bf2f(h)) : h;      // v-h exact (Sterbenz)
        }
        *(uint4*)(ebP + (size_t)idx * 8) = out;
    } else if (bb < 260) {
        const int k = (bb - 256) * 256 + t;
        see[k] = np_sumsq256(emb + (size_t)k * 256, 1);
        if (k == 0) { *cnt = 0; *loss = 0.0; }
    } else {
        // transpose 16 codes -> eT[c][k] (in d_out's quantized region; k2r reads, k3 overwrites)
        __shared__ float T[256][17];
        const int k0 = (bb - 260) << 4;
        const int kr = t >> 4, cs = (t & 15) << 4;
#pragma unroll
        for (int j = 0; j < 4; j++) {
            const float4 v = *(const float4*)(emb + (size_t)(k0 + kr) * 256 + cs + j * 4);
            T[cs + j * 4 + 0][kr] = v.x;
            T[cs + j * 4 + 1][kr] = v.y;
            T[cs + j * 4 + 2][kr] = v.z;
            T[cs + j * 4 + 3][kr] = v.w;
        }
        __syncthreads();
        float* dst = eT + (size_t)t * 1024 + k0;
#pragma unroll
        for (int j = 0; j < 4; j++) {
            float4 v;
            v.x = T[t][j * 4 + 0]; v.y = T[t][j * 4 + 1];
            v.z = T[t][j * 4 + 2]; v.w = T[t][j * 4 + 3];
            *(float4*)(dst + j * 4) = v;
        }
    }
}

// issue 8 B-loads (4 ct, hi+lo) into a register buffer -- static indices only
#define LOADB(buf, ccv, cth) do {                                              \
    _Pragma("unroll")                                                          \
    for (int q = 0; q < 4; q++) {                                              \
        const int ctq = (cth) * 4 + q;                                         \
        const size_t bbq = ((((size_t)codeg * 8 + (ccv)) * 8 + ctq) * 2) * 512 \
                           + (size_t)l * 8;                                    \
        buf[2 * q]     = *(const short8v*)(ebP + bbq);                         \
        buf[2 * q + 1] = *(const short8v*)(ebP + bbq + 512);                   \
    }                                                                          \
} while (0)

// 12 MFMAs for one ct (3-product accumulate) -- order identical to rounds 14-22
#define MFMA_CT(ctv, BH, BL) do {                                              \
    _Pragma("unroll")                                                          \
    for (int at = 0; at < 4; at++) {                                           \
        acc[at][ctv] = __builtin_amdgcn_mfma_f32_16x16x32_bf16(ah[at], BH, acc[at][ctv], 0, 0, 0); \
        acc[at][ctv] = __builtin_amdgcn_mfma_f32_16x16x32_bf16(ah[at], BL, acc[at][ctv], 0, 0, 0); \
        acc[at][ctv] = __builtin_amdgcn_mfma_f32_16x16x32_bf16(al[at], BH, acc[at][ctv], 0, 0, 0); \
    }                                                                          \
} while (0)

// ---------------- k1: fused stage+split+sxx+MFMA screen+loss (B double-buffered) ----------------
// Round-22 configuration (session best: 178.6 us total, k1 ~81 us). Round 23's
// in-k1 rescan fusion regressed k1 2x (barrier-laden tail at 1 block/CU) -- the
// separate small k2r launch amortizes flagged rows across idle CUs far better.
__global__ __launch_bounds__(512, 2) void k1_mfma(
        const float* __restrict__ x,
        const unsigned short* __restrict__ ebP,
        const float* __restrict__ see_g,
        float* __restrict__ sxx_g,
        unsigned long long* __restrict__ key,
        double* __restrict__ loss,
        int* __restrict__ cnt, int* __restrict__ wl) {
    __shared__ char smem[131072];
    unsigned long long* lk1 = (unsigned long long*)smem;          // [64][8] 4 KB (aliases xstage)
    float*              lg2 = (float*)(smem + 4096);              // [64][8] 2 KB
    float* xstage = (float*)smem;
    char*  frag   = smem + 65536;

    const int t = threadIdx.x;
    const int w = t >> 6, l = t & 63;
    const int codeg = w;
    const int lrow = l >> 4, lcol = l & 15;
    const int rb = blockIdx.x;
    const int n0 = rb * 64;
    const int b  = rb >> 4;
    const int hw0 = (rb & 15) << 6;

    // Phase A: stage x -> LDS [c][row] f32 (64 KB, linear GLD16)
    {
        const char* xbyte = (const char*)x + ((size_t)b * 262144 + hw0) * 4;
#pragma unroll
        for (int i = 0; i < 8; i++) {
            const int cbase = i * 32 + w * 4;
            const char* src = xbyte + (size_t)(cbase + (l >> 4)) * 4096 + (size_t)(l & 15) * 16;
            GLD16(src, smem + cbase * 256);
        }
    }
    __syncthreads();

    // Phase C: cooperative bf16 hi/lo split -> packed fragments
#pragma unroll
    for (int ii = 0; ii < 4; ii++) {
        const int pi  = ii * 512 + t;          // 0..2047 = [cc(8)][at(4)][l(64)]
        const int pcc = pi >> 8;
        const int pat = (pi >> 6) & 3;
        const int pl  = pi & 63;
        const int prow = pat * 16 + (pl & 15);
        const int pc0  = pcc * 32 + (pl >> 4) * 8;
        uint4 hp, lp;
        unsigned short* hpp = (unsigned short*)&hp;
        unsigned short* lpp = (unsigned short*)&lp;
#pragma unroll
        for (int i = 0; i < 8; i++) {
            const float v = xstage[(pc0 + i) * 64 + prow];
            const unsigned short h = f2bf(v);
            hpp[i] = h;
            lpp[i] = f2bf(v - bf2f(h));        // exact (Sterbenz)
        }
        char* dst = frag + pcc * 8192 + pat * 2048 + pl * 16;
        *(uint4*)dst = hp;
        *(uint4*)(dst + 1024) = lp;
    }
    // Phase B: per-row ||x||^2, np-exact (wave 0; one row per lane)
    float sx_reg = 0.f;
    if (t < 64) {
        sx_reg = np_sumsq256(xstage + t, 64);
        sxx_g[n0 + t] = sx_reg;
    }
    __syncthreads();                            // frags+sxx ready; xstage dead

    float4v acc[4][8];
#pragma unroll
    for (int at = 0; at < 4; at++)
#pragma unroll
        for (int ct = 0; ct < 8; ct++) acc[at][ct] = (float4v){0.f, 0.f, 0.f, 0.f};

    short8v b0[8], b1[8];
    LOADB(b0, 0, 0);                            // prime: (cc=0, half 0)
    for (int cc = 0; cc < 8; cc++) {
        short8v ah[4], al[4];
#pragma unroll
        for (int at = 0; at < 4; at++) {
            const int off = cc * 8192 + at * 2048 + l * 16;
            ah[at] = *(const short8v*)(frag + off);
            al[at] = *(const short8v*)(frag + off + 1024);
        }
        LOADB(b1, cc, 1);                       // issue half 1 before computing half 0
        MFMA_CT(0, b0[0], b0[1]);
        MFMA_CT(1, b0[2], b0[3]);
        MFMA_CT(2, b0[4], b0[5]);
        MFMA_CT(3, b0[6], b0[7]);
        if (cc < 7) LOADB(b0, cc + 1, 0);       // issue next cc's half 0 under half 1's MFMAs
        MFMA_CT(4, b1[0], b1[1]);
        MFMA_CT(5, b1[2], b1[3]);
        MFMA_CT(6, b1[4], b1[5]);
        MFMA_CT(7, b1[6], b1[7]);
    }

    float sv[8];
#pragma unroll
    for (int ct = 0; ct < 8; ct++) sv[ct] = see_g[codeg * 128 + ct * 16 + lcol];

    // per-row top-2 of g = see - 2*dot_est  (sxx row-constant: order-neutral)
#pragma unroll
    for (int at = 0; at < 4; at++) {
#pragma unroll
        for (int j = 0; j < 4; j++) {
            unsigned long long K1 = ~0ull; float G1 = FLT_BIG, G2 = FLT_BIG;
#pragma unroll
            for (int ct = 0; ct < 8; ct++) {
                const float g = fmaf(-2.f, acc[at][ct][j], sv[ct]);
                const int k = codeg * 128 + ct * 16 + lcol;
                const unsigned long long pk =
                    ((unsigned long long)f32_sortable(g) << 32) | (unsigned int)k;
                if (pk < K1) { G2 = G1; K1 = pk; G1 = g; }
                else         { G2 = fminf(G2, g); }
            }
#pragma unroll
            for (int m = 1; m < 16; m <<= 1) {
                const unsigned long long oK = __shfl_xor(K1, m, 64);
                const float oG2 = __shfl_xor(G2, m, 64);
                const float oG1 = f32_unsortable((unsigned int)(oK >> 32));
                if (oK < K1) { G2 = fminf(oG2, G1); K1 = oK; G1 = oG1; }
                else         { G2 = fminf(G2, oG1); }
            }
            const int rloc = at * 16 + lrow * 4 + j;
            if (lcol == 0) { lk1[rloc * 8 + codeg] = K1; lg2[rloc * 8 + codeg] = G2; }
        }
    }
    __syncthreads();
    if (t < 64) {
        unsigned long long K1 = ~0ull; float G1 = FLT_BIG, G2 = FLT_BIG;
        for (int cg = 0; cg < 8; cg++) {
            const unsigned long long oK = lk1[t * 8 + cg];
            const float oG2 = lg2[t * 8 + cg];
            const float oG1 = f32_unsortable((unsigned int)(oK >> 32));
            if (oK < K1) { G2 = fminf(oG2, G1); K1 = oK; G1 = oG1; }
            else         { G2 = fminf(G2, oG1); }
        }
        const int n = n0 + t;
        if (G2 - G1 > MARGIN) { key[n] = K1; }
        else { key[n] = ~0ull; wl[atomicAdd(cnt, 1)] = n; }
        // loss partial: sum over this block's 64 rows of (sxx + min-dist est)
        float part = sx_reg + G1;
#pragma unroll
        for (int m = 1; m < 64; m <<= 1) part += __shfl_xor(part, m, 64);
        if (t == 0) atomicAdd(loss, (double)part);
    }
}

// ---------------- k2r: np-exact fp32-chain rescan (coalesced via eT in d_out) ----------------
__global__ __launch_bounds__(256) void k2r(const float* __restrict__ x,
                                           const float* __restrict__ eT,
                                           const float* __restrict__ see,
                                           const float* __restrict__ sxx,
                                           unsigned long long* __restrict__ key,
                                           const int* __restrict__ cnt,
                                           const int* __restrict__ wl) {
    __shared__ float xs[8][264];
    const int t = threadIdx.x;
    const int total = *cnt;
    for (int base = blockIdx.x * 8; base < total; base += 128 * 8) {
        int nrow[8]; float sx8[8];
#pragma unroll
        for (int r = 0; r < 8; r++) {
            int idx = base + r; if (idx >= total) idx = total - 1;   // benign dup
            const int n = wl[idx];
            nrow[r] = n; sx8[r] = sxx[n];
        }
        __syncthreads();                 // prior batch's xs reads done
#pragma unroll
        for (int r = 0; r < 8; r++) {
            const int n = nrow[r];
            xs[r][t] = x[(size_t)(n >> 10) * 262144 + (size_t)t * 1024 + (n & 1023)];
        }
        __syncthreads();
        float d[8][4];
#pragma unroll
        for (int r = 0; r < 8; r++)
#pragma unroll
            for (int j = 0; j < 4; j++) d[r][j] = 0.f;
#pragma unroll 4
        for (int c = 0; c < 256; c++) {
            float ev[4];
#pragma unroll
            for (int j = 0; j < 4; j++) ev[j] = eT[(size_t)c * 1024 + t + 256 * j];
#pragma unroll
            for (int r = 0; r < 8; r++) {
                const float xv = xs[r][c];
                d[r][0] = fmaf(xv, ev[0], d[r][0]);
                d[r][1] = fmaf(xv, ev[1], d[r][1]);
                d[r][2] = fmaf(xv, ev[2], d[r][2]);
                d[r][3] = fmaf(xv, ev[3], d[r][3]);
            }
        }
#pragma unroll
        for (int r = 0; r < 8; r++) {
            unsigned long long best = ~0ull;
#pragma unroll
            for (int j = 0; j < 4; j++) {
                const float q = fmaf(-2.f, d[r][j], sx8[r]) + see[t + 256 * j];
                const unsigned long long pk =
                    ((unsigned long long)f32_sortable(q) << 32) | (unsigned int)(t + 256 * j);
                best = pk < best ? pk : best;
            }
            atomicMin(&key[nrow[r]], best);
        }
    }
}

// ---------------- k3: gather quantized + indices + loss finalize ----------------
__global__ __launch_bounds__(256) void k3_out(const float* __restrict__ emb,
                                              const unsigned long long* __restrict__ key,
                                              const double* __restrict__ loss,
                                              float* __restrict__ dout) {
    __shared__ float elds[32][257];
    __shared__ int   idxs[32];
    const int t  = threadIdx.x;
    const int bh = blockIdx.x;
    const int b = bh >> 5, h = bh & 31;
    if (t < 32) idxs[t] = (int)(key[(bh << 5) + t] & 0xffffffffull);
    __syncthreads();
    for (int r = 0; r < 32; r++) elds[r][t] = emb[(size_t)idxs[r] * 256 + t];
    __syncthreads();
    const int w = t & 31, cg = t >> 5;
    const size_t base = (size_t)b * 262144 + (size_t)(h * 32 + w);
#pragma unroll 4
    for (int s = 0; s < 32; s++) {
        const int c = (cg << 5) + s;
        dout[base + (size_t)c * 1024] = elds[w][c];
    }
    if (t < 32) dout[IDX_OFF + (bh << 5) + t] = (float)idxs[t];
    if (bh == 0 && t == 0)
        dout[LOSS_OFF] = (float)(1.25 * (*loss) / 8388608.0);
}

extern "C" void kernel_launch(void* const* d_in, const int* in_sizes, int n_in,
                              void* d_out, int out_size, void* d_ws, size_t ws_size,
                              hipStream_t stream) {
    const float* x   = (const float*)d_in[0];
    const float* emb = (const float*)d_in[1];
    float* dout = (float*)d_out;
    char* ws = (char*)d_ws;
    float*  see  = (float*)(ws + WS_SEE);
    float*  sxx  = (float*)(ws + WS_SXX);
    unsigned long long* key = (unsigned long long*)(ws + WS_KEY);
    int*    cnt  = (int*)(ws + WS_CNT);
    double* loss = (double*)(ws + WS_LOSS);
    int*    wl   = (int*)(ws + WS_WL);
    unsigned short* ebP = (unsigned short*)(ws + WS_EP);
    // eT (exact f32 transpose for k2r) lives in d_out's quantized region:
    // written by k_prep, read by k2r, overwritten by k3.
    float* eT = dout;

    k_prep <<<324,  256, 0, stream>>>(emb, ebP, see, eT, cnt, loss);
    k1_mfma<<<512,  512, 0, stream>>>(x, ebP, see, sxx, key, loss, cnt, wl);
    k2r    <<<128,  256, 0, stream>>>(x, eT, see, sxx, key, cnt, wl);
    k3_out <<<1024, 256, 0, stream>>>(emb, key, loss, dout);
}